// Round 1
// baseline (89.584 us; speedup 1.0000x reference)
//
#include <hip/hip_runtime.h>
#include <math.h>

// out[p, o] = sum_c sech(in[p, c] * kernel[o] + bias[o]),  p in [0, B*H*W), o in [0, 11)
// sech(x) = 2*e^{-|x|} / (1 + e^{-2|x|})  (stable; ±inf input -> 0 automatically)

__global__ __launch_bounds__(256) void HistoMaker_kernel(
    const float* __restrict__ in,     // [P, 3]
    const float* __restrict__ kern,   // [11]
    const float* __restrict__ bias,   // [11]
    float* __restrict__ out,          // [P, 11]
    int n_out)
{
    int idx = blockIdx.x * blockDim.x + threadIdx.x;
    if (idx >= n_out) return;

    unsigned u = (unsigned)idx;
    unsigned p = u / 11u;             // magic-multiply, compiler-generated
    unsigned o = u - p * 11u;

    float k = kern[o];
    float b = bias[o];

    const float* ip = in + (size_t)p * 3u;
    float s = 0.0f;
#pragma unroll
    for (int c = 0; c < 3; ++c) {
        float y = ip[c];
        float x = fabsf(fmaf(y, k, b));
        float e = __expf(-x);                       // e^{-|x|}
        s += __fdividef(2.0f * e, fmaf(e, e, 1.0f)); // 2e / (1 + e^2)
    }
    out[idx] = s;
}

extern "C" void kernel_launch(void* const* d_in, const int* in_sizes, int n_in,
                              void* d_out, int out_size, void* d_ws, size_t ws_size,
                              hipStream_t stream) {
    const float* image  = (const float*)d_in[0];  // [16*512*512*3]
    const float* kernel = (const float*)d_in[1];  // [11]
    const float* bias   = (const float*)d_in[2];  // [11]
    float* out = (float*)d_out;                   // [16*512*512*11]

    int n_out = out_size;
    int block = 256;
    int grid = (n_out + block - 1) / block;
    HistoMaker_kernel<<<grid, block, 0, stream>>>(image, kernel, bias, out, n_out);
}

// Round 3
// 62.869 us; speedup vs baseline: 1.4249x; 1.4249x over previous
//
#include <hip/hip_runtime.h>
#include <math.h>

// out[p, o] = sum_c sech(in[p,c] * kern[o] + bias[o]),  p in [0,P), o in [0,11)
// sech(x) = 2*e^{-|x|} / (1 + e^{-2|x|});  e^{-|x|} = exp2(-|x * log2e|)
// Fold log2e into k,b:  x' = y*(k*log2e) + b*log2e;  |x'| = |x|*log2e.
// y = +/-inf -> e = exp2(-inf) = 0 -> contribution 0 (matches isinf mask; kern[o] != 0).

#define LOG2E 1.44269504088896340736f

typedef float floatx4 __attribute__((ext_vector_type(4)));

__global__ __launch_bounds__(256) void HistoMaker_kernel(
    const float* __restrict__ in,     // [P, 3]
    const float* __restrict__ kern,   // [11]
    const float* __restrict__ bias,   // [11]
    float* __restrict__ out,          // [P, 11]
    int n_quads,                      // out_size / 4
    int n_out,                        // total outputs
    int P)                            // pixel count
{
    int q = blockIdx.x * blockDim.x + threadIdx.x;
    if (q >= n_quads) return;

    unsigned base = 4u * (unsigned)q;          // first output index of this thread
    unsigned p0 = base / 11u;                  // magic-multiply
    unsigned o0 = base - p0 * 11u;
    unsigned p1 = p0 + 1u;
    if (p1 >= (unsigned)P) p1 = (unsigned)P - 1u;

    // Load the (up to) two pixels this quad can touch.
    const float* ia = in + (size_t)p0 * 3u;
    const float* ib = in + (size_t)p1 * 3u;
    float a0 = ia[0], a1 = ia[1], a2 = ia[2];
    float c0 = ib[0], c1 = ib[1], c2 = ib[2];

    float res[4];
#pragma unroll
    for (int j = 0; j < 4; ++j) {
        unsigned o = o0 + (unsigned)j;
        bool wrap = (o >= 11u);
        if (wrap) o -= 11u;
        float y0 = wrap ? c0 : a0;
        float y1 = wrap ? c1 : a1;
        float y2 = wrap ? c2 : a2;

        float k2 = kern[o] * LOG2E;
        float b2 = bias[o] * LOG2E;

        float s;
        {
            float x = fmaf(y0, k2, b2);
            float e = __builtin_amdgcn_exp2f(-fabsf(x));
            float r = __builtin_amdgcn_rcpf(fmaf(e, e, 1.0f));
            s = (e + e) * r;
        }
        {
            float x = fmaf(y1, k2, b2);
            float e = __builtin_amdgcn_exp2f(-fabsf(x));
            float r = __builtin_amdgcn_rcpf(fmaf(e, e, 1.0f));
            s = fmaf(e + e, r, s);
        }
        {
            float x = fmaf(y2, k2, b2);
            float e = __builtin_amdgcn_exp2f(-fabsf(x));
            float r = __builtin_amdgcn_rcpf(fmaf(e, e, 1.0f));
            s = fmaf(e + e, r, s);
        }
        res[j] = s;
    }

    if (base + 3u < (unsigned)n_out) {
        floatx4 v = { res[0], res[1], res[2], res[3] };
        __builtin_nontemporal_store(v, (floatx4*)(out + base));
    } else {
        for (int j = 0; j < 4; ++j) {
            unsigned idx = base + (unsigned)j;
            if (idx < (unsigned)n_out) out[idx] = res[j];
        }
    }
}

extern "C" void kernel_launch(void* const* d_in, const int* in_sizes, int n_in,
                              void* d_out, int out_size, void* d_ws, size_t ws_size,
                              hipStream_t stream) {
    const float* image  = (const float*)d_in[0];  // [16*512*512*3]
    const float* kernel = (const float*)d_in[1];  // [11]
    const float* bias   = (const float*)d_in[2];  // [11]
    float* out = (float*)d_out;                   // [16*512*512*11]

    int n_out = out_size;
    int P = in_sizes[0] / 3;
    int n_quads = (n_out + 3) / 4;
    int block = 256;
    int grid = (n_quads + block - 1) / block;
    HistoMaker_kernel<<<grid, block, 0, stream>>>(image, kernel, bias, out,
                                                  n_quads, n_out, P);
}

// Round 4
// 39.398 us; speedup vs baseline: 2.2739x; 1.5957x over previous
//
#include <hip/hip_runtime.h>
#include <math.h>

// out[p, o] = sum_c sech(in[p,c] * kern[o] + bias[o]),  p in [0,P), o in [0,11)
// sech(x) = 2*e^{-|x|} / (1 + e^{-2|x|});  e^{-|x|} = exp2(-(|x|*log2e))
// log2e folded into k,b. y=+/-inf -> e=0 -> contribution 0 (matches isinf mask).
//
// Structure: 256 threads = 256 pixels per block (P = 4194304 = 16384*256, no tail).
// Planar compute with wave-uniform o (kern/bias become s_load), results staged in
// LDS [pixel][o], then transposed coalesced float4 NT stores (704 per block).

#define LOG2E 1.44269504088896340736f

typedef float floatx4 __attribute__((ext_vector_type(4)));

__global__ __launch_bounds__(256) void HistoMaker_kernel(
    const float* __restrict__ in,     // [P, 3]
    const float* __restrict__ kern,   // [11]
    const float* __restrict__ bias,   // [11]
    float* __restrict__ out)          // [P, 11]
{
    __shared__ __align__(16) float lds[256 * 11];

    const int t = threadIdx.x;
    const size_t pb = (size_t)blockIdx.x * 256;   // base pixel of this block

    const float* ip = in + (pb + (unsigned)t) * 3u;
    float y0 = ip[0], y1 = ip[1], y2 = ip[2];     // dwordx3, coalesced

#pragma unroll
    for (int o = 0; o < 11; ++o) {
        float k2 = kern[o] * LOG2E;               // uniform -> scalar load
        float b2 = bias[o] * LOG2E;

        float x0 = fmaf(y0, k2, b2);
        float e0 = __builtin_amdgcn_exp2f(-fabsf(x0));
        float s  = e0 * __builtin_amdgcn_rcpf(fmaf(e0, e0, 1.0f));

        float x1 = fmaf(y1, k2, b2);
        float e1 = __builtin_amdgcn_exp2f(-fabsf(x1));
        s = fmaf(e1, __builtin_amdgcn_rcpf(fmaf(e1, e1, 1.0f)), s);

        float x2 = fmaf(y2, k2, b2);
        float e2 = __builtin_amdgcn_exp2f(-fabsf(x2));
        s = fmaf(e2, __builtin_amdgcn_rcpf(fmaf(e2, e2, 1.0f)), s);

        lds[t * 11 + o] = s + s;                  // 2 * sum(e*r)
    }

    __syncthreads();

    // 256*11 floats = 704 float4 slots; thread t writes slots t, t+256, t+512(<704)
    float* ob = out + pb * 11u;
#pragma unroll
    for (int j = 0; j < 3; ++j) {
        int slot = t + j * 256;
        if (slot < 704) {
            floatx4 v = *(const floatx4*)&lds[4 * slot];
            __builtin_nontemporal_store(v, (floatx4*)(ob + 4 * slot));
        }
    }
}

extern "C" void kernel_launch(void* const* d_in, const int* in_sizes, int n_in,
                              void* d_out, int out_size, void* d_ws, size_t ws_size,
                              hipStream_t stream) {
    const float* image  = (const float*)d_in[0];  // [16*512*512*3]
    const float* kernel = (const float*)d_in[1];  // [11]
    const float* bias   = (const float*)d_in[2];  // [11]
    float* out = (float*)d_out;                   // [16*512*512*11]

    int P = in_sizes[0] / 3;                      // 4194304
    int grid = P / 256;                           // 16384, exact
    HistoMaker_kernel<<<grid, 256, 0, stream>>>(image, kernel, bias, out);
}